// Round 8
// baseline (1357.949 us; speedup 1.0000x reference)
//
#include <hip/hip_runtime.h>
#include <cstdint>
#include <cstddef>

// RNG scheme for reproducing jax.random.uniform(jax.random.key(42), (8,2048,16,512)):
//   0: threefry_partitionable (counter = (0, i)), bits = out0 ^ out1   [verified passing]
#define RNG_SCHEME 0

#define N_TOK 16384      // B*T
#define DIM   1024       // D
#define NGRP  16         // V
#define NCODE 512        // K
#define GDIM  64         // d

// ---------------- Threefry-2x32, key = (0, 42) ----------------
__device__ __forceinline__ uint2 threefry_0_42(uint32_t x0, uint32_t x1) {
  const uint32_t ks0 = 0u;
  const uint32_t ks1 = 42u;
  const uint32_t ks2 = 0x1BD11BDAu ^ 0u ^ 42u;
  x0 += ks0; x1 += ks1;
#define TF_R(r) { x0 += x1; x1 = (x1 << (r)) | (x1 >> (32 - (r))); x1 ^= x0; }
  TF_R(13) TF_R(15) TF_R(26) TF_R(6)
  x0 += ks1; x1 += ks2 + 1u;
  TF_R(17) TF_R(29) TF_R(16) TF_R(24)
  x0 += ks2; x1 += ks0 + 2u;
  TF_R(13) TF_R(15) TF_R(26) TF_R(6)
  x0 += ks0; x1 += ks1 + 3u;
  TF_R(17) TF_R(29) TF_R(16) TF_R(24)
  x0 += ks1; x1 += ks2 + 4u;
  TF_R(13) TF_R(15) TF_R(26) TF_R(6)
  x0 += ks2; x1 += ks0 + 5u;
#undef TF_R
  return make_uint2(x0, x1);
}

// u in [0,1) exactly as jax: (bits>>9 | 0x3f800000) bitcast - 1.0f
__device__ __forceinline__ float u_from_bits(uint32_t bits) {
  return __uint_as_float((bits >> 9) | 0x3f800000u) - 1.0f;
}

// gumbel = -log(-log(u+1e-8) + 1e-8), ops ordered as the reference.
// fp-monotone nondecreasing in bits (every step is monotone).
__device__ __forceinline__ float gumbel_from_bits(uint32_t bits) {
  float u = u_from_bits(bits);
  float w = (-logf(u + 1e-8f)) + 1e-8f;
  return -logf(w);
}

// monotone float->uint map: preserves total order for non-NaN; equal iff bit-identical
__device__ __forceinline__ uint32_t mono_u32(float z) {
  uint32_t b = __float_as_uint(z);
  return b ^ ((uint32_t)(((int32_t)b) >> 31) | 0x80000000u);
}

// ---------------- zero helper ----------------
__global__ __launch_bounds__(256) void k_zero(float* __restrict__ p, int n) {
  int i = blockIdx.x * 256 + threadIdx.x;
  if (i < n) p[i] = 0.f;
}

// ---------------- c2 table + per-group threshold ----------------
// c2tab[v][k] = |c_vk|^2 (same d4-ascending tree as the old in-kernel c2a).
// thrv[v] = 2*max_k|c_vk| + 0.01  (g-space exclusion threshold; the 0.01 slack
// dominates every fp rounding in the bound chain).
__global__ __launch_bounds__(512) void k_c2(const float* __restrict__ cb,
                                            float* __restrict__ c2tab,
                                            float* __restrict__ thrv) {
  const int v = blockIdx.x, k = threadIdx.x;  // 16 x 512
  const float* cp = cb + (size_t)(v * NCODE + k) * GDIM;
  float s = 0.f;
#pragma unroll 4
  for (int d4 = 0; d4 < 16; ++d4) {
    float4 c = *(const float4*)(cp + d4 * 4);
    s += c.x * c.x + c.y * c.y + c.z * c.z + c.w * c.w;
  }
  c2tab[v * NCODE + k] = s;
  float m = s;
#pragma unroll
  for (int off = 1; off < 64; off <<= 1) m = fmaxf(m, __shfl_xor(m, off, 64));
  __shared__ float pm[8];
  if ((k & 63) == 0) pm[k >> 6] = m;
  __syncthreads();
  if (k == 0) {
    float mm = pm[0];
#pragma unroll
    for (int w = 1; w < 8; ++w) mm = fmaxf(mm, pm[w]);
    thrv[v] = 2.0f * sqrtf(mm) + 0.01f;
  }
}

// ---------------- fp32 NT GEMM, 128x64 tile, BK=32 ----------------
// C[M,N] = A[M,K] * B[N,K]^T + bias[N];  M=16384, N=K=1024. 256 thr, 8x4/thr.
// BK=32 (was 16): halves the barrier count (64 vs 128 per block) and doubles
// FMA per staging event. Same single-buffer stage->barrier->compute structure
// as the measured-good BK=16 version -- NO register-held prefetch across the
// compute loop (round-6 failure: 124 VGPR). Values and per-output k-ascending
// accumulation order bit-identical. red (q2 scratch) overlays as[], guarded by
// a barrier after the last compute.
__global__ __launch_bounds__(256) void gemm_nt(
    const float* __restrict__ A, const float* __restrict__ B,
    const float* __restrict__ bias, float* __restrict__ C,
    const float* __restrict__ cbk, const int* __restrict__ gidx,
    float* __restrict__ q2w)
{
  __shared__ float as[32 * 132];   // [k][m], stride 132 (16896 B)
  __shared__ float bs[32 * 68];    // [k][n], stride 68  (8704 B)
  float* red = as;                 // [128][16] q2 overlay (2048 <= 4224 floats)

  const int tid = threadIdx.x;
  const int tx = tid & 15;         // n
  const int ty = tid >> 4;         // m
  const int m0 = blockIdx.x * 128;
  const int n0 = blockIdx.y * 64;

  float acc[8][4] = {};

  for (int kt = 0; kt < 32; ++kt) {
    __syncthreads();
    // stage A: 4 float4 / thread (128 rows x 32 k); f -> m_l = f>>3, k4 = f&7
#pragma unroll
    for (int i = 0; i < 4; ++i) {
      int f = tid + 256 * i;
      int m_l = f >> 3, k4 = f & 7;
      const float* src;
      if (gidx) {
        int vp = kt >> 1;                      // 64-k group = 2 K-tiles
        int row = gidx[(m0 + m_l) * NGRP + vp];
        src = cbk + ((size_t)(vp * NCODE + row) * GDIM + (kt & 1) * 32 + k4 * 4);
      } else {
        src = A + ((size_t)(m0 + m_l) * DIM + kt * 32 + k4 * 4);
      }
      float4 a4 = *(const float4*)src;
      as[(k4 * 4 + 0) * 132 + m_l] = a4.x;
      as[(k4 * 4 + 1) * 132 + m_l] = a4.y;
      as[(k4 * 4 + 2) * 132 + m_l] = a4.z;
      as[(k4 * 4 + 3) * 132 + m_l] = a4.w;
    }
    // stage B: 2 float4 / thread (64 rows x 32 k)
#pragma unroll
    for (int i = 0; i < 2; ++i) {
      int f = tid + 256 * i;
      int n_l = f >> 3, k4 = f & 7;
      float4 b4 = *(const float4*)(B + ((size_t)(n0 + n_l) * DIM + kt * 32 + k4 * 4));
      bs[(k4 * 4 + 0) * 68 + n_l] = b4.x;
      bs[(k4 * 4 + 1) * 68 + n_l] = b4.y;
      bs[(k4 * 4 + 2) * 68 + n_l] = b4.z;
      bs[(k4 * 4 + 3) * 68 + n_l] = b4.w;
    }
    __syncthreads();
#pragma unroll
    for (int k = 0; k < 32; ++k) {
      float4 a0 = *(const float4*)&as[k * 132 + ty * 8];
      float4 a1 = *(const float4*)&as[k * 132 + ty * 8 + 4];
      float4 b0 = *(const float4*)&bs[k * 68 + tx * 4];
      float av[8] = {a0.x, a0.y, a0.z, a0.w, a1.x, a1.y, a1.z, a1.w};
      float bv[4] = {b0.x, b0.y, b0.z, b0.w};
#pragma unroll
      for (int r = 0; r < 8; ++r)
#pragma unroll
        for (int j = 0; j < 4; ++j) acc[r][j] += av[r] * bv[j];
    }
  }

  const float4 bb = *(const float4*)(bias + n0 + tx * 4);
  if (q2w) __syncthreads();  // all as-reads done before red overlays as
#pragma unroll
  for (int r = 0; r < 8; ++r) {
    const int m = m0 + ty * 8 + r;
    float4 c;
    c.x = acc[r][0] + bb.x; c.y = acc[r][1] + bb.y;
    c.z = acc[r][2] + bb.z; c.w = acc[r][3] + bb.w;
    *(float4*)(C + (size_t)m * DIM + n0 + tx * 4) = c;
    if (q2w) red[(ty * 8 + r) * 16 + tx] = c.x * c.x + c.y * c.y + c.z * c.z + c.w * c.w;
  }
  if (q2w) {
    __syncthreads();
    if (tid < 128) {
      float s = 0.f;
#pragma unroll
      for (int x = 0; x < 16; ++x) s += red[tid * 16 + x];
      q2w[(size_t)(m0 + tid) * NGRP + blockIdx.y] = s;
    }
  }
}

// ---------------- candidate scoring helper (exact z) ----------------
__device__ __forceinline__ unsigned long long cand_key(
    const float* __restrict__ qp, const float* __restrict__ cp,
    float c2k, float q2v, uint32_t bits, int k)
{
  float acc = 0.f;
#pragma unroll 4
  for (int d4 = 0; d4 < 16; ++d4) {
    float4 qv = *(const float4*)(qp + d4 * 4);
    float4 cv = *(const float4*)(cp + d4 * 4);
    acc += qv.x * cv.x + qv.y * cv.y + qv.z * cv.z + qv.w * cv.w;
  }
  float g = gumbel_from_bits(bits);
  float z = (-sqrtf(fmaxf((q2v + c2k) - 2.0f * acc, 0.0f))) + g;
  return ((unsigned long long)mono_u32(z) << 32) | (uint32_t)(1023 - k);
}

// ---------------- K2: wave-per-token, barrier-free (round-7, verified) ----------
// grid (4096, 16), 256 thr = 4 waves. Wave wv owns token blockIdx.x*4+wv for
// group v; lane owns codes k = lane + 64*i, i=0..7. All reductions are 64-lane
// shfl butterflies: NO __syncthreads, NO LDS.
__global__ __launch_bounds__(256) void k2_select(
    const float* __restrict__ q, const float* __restrict__ q2w,
    const float* __restrict__ cb, const float* __restrict__ c2tab,
    const float* __restrict__ thrv, float* __restrict__ counts,
    int* __restrict__ idxw)
{
  const int tid = threadIdx.x;
  const int lane = tid & 63, wv = tid >> 6;
  const int v   = blockIdx.y;                  // 0..15
  const int tok = blockIdx.x * 4 + wv;         // 0..16383

  // phase A: threefry bits for my 8 codes (exact stream: ctr = base + k)
  const uint32_t base = ((uint32_t)(tok * NGRP + v)) << 9;
  uint32_t bits[8];
#pragma unroll
  for (int i = 0; i < 8; ++i) {
    uint2 r = threefry_0_42(0u, base + (uint32_t)(lane + 64 * i));
    bits[i] = r.x ^ r.y;
  }

  // phase B: wave max of bits (== max u == max g, fp-monotone)
  uint32_t m = bits[0];
#pragma unroll
  for (int i = 1; i < 8; ++i) m = bits[i] > m ? bits[i] : m;
#pragma unroll
  for (int off = 1; off < 64; off <<= 1) {
    uint32_t o = __shfl_xor(m, off, 64);
    if (o > m) m = o;
  }

  // phase C: u* threshold (wave-uniform; every lane computes it)
  const float gmax = gumbel_from_bits(m);
  const float inner = gmax - thrv[v];
  const float wstar = expf(-inner) - 1e-8f;    // > 0 since inner <= ~16
  const float ustar = expf(-wstar) - 1e-8f - 1e-6f;

  // phase D: surviving candidates evaluate exact z; packed-u64 wave argmax
  const float q2v = q2w[tok * NGRP + v];
  const float* qp = q + (size_t)tok * DIM + v * GDIM;
  unsigned long long K = 0ull;
#pragma unroll 1
  for (int i = 0; i < 8; ++i) {
    if (u_from_bits(bits[i]) >= ustar) {
      const int k = lane + 64 * i;
      unsigned long long t = cand_key(qp, cb + (size_t)(v * NCODE + k) * GDIM,
                                      c2tab[v * NCODE + k], q2v, bits[i], k);
      if (t > K) K = t;
    }
  }
#pragma unroll
  for (int off = 1; off < 64; off <<= 1) {
    unsigned long long O = __shfl_xor(K, off, 64);
    if (O > K) K = O;
  }

  if (lane == 0) {
    // fi in [0,511] always (max-bits lane passes its own filter); '&511'
    // hardens the impossible K==0 path against an OOB write.
    const int fi = (1023 - (int)(K & 0xFFFFFFFFu)) & 511;
    idxw[tok * NGRP + v] = fi;
    atomicAdd(&counts[v * NCODE + fi], 1.0f);
  }
}

// ---------------- targets ----------------
__global__ __launch_bounds__(256) void k_targets(const int* __restrict__ idxw, float* __restrict__ out) {
  int bt = blockIdx.x * 256 + threadIdx.x;  // 0..16383
  const int* p = idxw + bt * NGRP;
  int s = 0;
#pragma unroll
  for (int v = 0; v < NGRP; ++v) s += p[v] * (v * NCODE);
  out[bt] = (float)s;
}

// ---------------- diversity loss ----------------
__global__ __launch_bounds__(512) void k_losses(const float* __restrict__ counts, float* __restrict__ out) {
  __shared__ float partial[8];
  const int k = threadIdx.x;           // 0..511
  const int lane = k & 63, wv = k >> 6;
  const float invN = 1.0f / 16384.0f;  // pow2: identical to division
  const float logK = logf(512.0f);
  float total = 0.f;
  for (int v = 0; v < NGRP; ++v) {
    float p = counts[v * NCODE + k] * invN;
    float term = p * logf(p + 1e-8f);
    float s = term;
#pragma unroll
    for (int off = 1; off < 64; off <<= 1) s += __shfl_xor(s, off, 64);
    if (lane == 0) partial[wv] = s;
    __syncthreads();
    if (k == 0) {
      float t = 0.f;
#pragma unroll
      for (int w = 0; w < 8; ++w) t += partial[w];
      float ent = -t;
      total += ent / logK;
    }
    __syncthreads();
  }
  if (k == 0) out[0] = 0.1f * (-(total / 16.0f));
}

// ---------------- launch ----------------
extern "C" void kernel_launch(void* const* d_in, const int* in_sizes, int n_in,
                              void* d_out, int out_size, void* d_ws, size_t ws_size,
                              hipStream_t stream) {
  const float* features  = (const float*)d_in[0];  // (8,2048,1024)
  const float* codebooks = (const float*)d_in[1];  // (16,512,64)
  const float* Wq   = (const float*)d_in[2];       // (1024,1024)
  const float* bq   = (const float*)d_in[3];       // (1024)
  const float* Wout = (const float*)d_in[4];       // (1024,1024)
  const float* bout = (const float*)d_in[5];       // (1024)

  float* out = (float*)d_out;
  float* quantized = out;                 // 16,777,216
  float* targets   = out + 16777216;      // 16,384
  float* losses    = out + 16793600;      // 1

  float* ws     = (float*)d_ws;
  float* q      = ws;                     // 16,777,216 f
  float* q2w    = ws + 16777216;          // 262,144 f
  float* counts = ws + 17039360;          // 8,192 f
  int*   idxw   = (int*)(ws + 17047552);  // 262,144 i  (total 69.2 MB)

  // c2 table + thresholds live in the quantized output region as scratch;
  // k2 is the only consumer, and gemm2 (last kernel) overwrites the region.
  float* c2tab = quantized;               // 8,192 f
  float* thrv  = quantized + 8192;        // 16 f

  hipLaunchKernelGGL(k_zero, dim3(32), dim3(256), 0, stream, counts, NGRP * NCODE);
  hipLaunchKernelGGL(k_c2, dim3(16), dim3(512), 0, stream, codebooks, c2tab, thrv);
  hipLaunchKernelGGL(gemm_nt, dim3(128, 16), dim3(256), 0, stream,
                     features, Wq, bq, q, (const float*)nullptr, (const int*)nullptr, q2w);
  hipLaunchKernelGGL(k2_select, dim3(4096, 16), dim3(256), 0, stream,
                     q, q2w, codebooks, c2tab, thrv, counts, idxw);
  hipLaunchKernelGGL(k_targets, dim3(64), dim3(256), 0, stream, idxw, targets);
  hipLaunchKernelGGL(k_losses, dim3(1), dim3(512), 0, stream, counts, losses);
  hipLaunchKernelGGL(gemm_nt, dim3(128, 16), dim3(256), 0, stream,
                     (const float*)nullptr, Wout, bout, quantized, codebooks, idxw,
                     (float*)nullptr);
}

// Round 10
// 1356.150 us; speedup vs baseline: 1.0013x; 1.0013x over previous
//
#include <hip/hip_runtime.h>
#include <cstdint>
#include <cstddef>

// RNG scheme for reproducing jax.random.uniform(jax.random.key(42), (8,2048,16,512)):
//   0: threefry_partitionable (counter = (0, i)), bits = out0 ^ out1   [verified passing]
#define RNG_SCHEME 0

#define N_TOK 16384      // B*T
#define DIM   1024       // D
#define NGRP  16         // V
#define NCODE 512        // K
#define GDIM  64         // d

// ---------------- Threefry-2x32, key = (0, 42) ----------------
__device__ __forceinline__ uint2 threefry_0_42(uint32_t x0, uint32_t x1) {
  const uint32_t ks0 = 0u;
  const uint32_t ks1 = 42u;
  const uint32_t ks2 = 0x1BD11BDAu ^ 0u ^ 42u;
  x0 += ks0; x1 += ks1;
#define TF_R(r) { x0 += x1; x1 = (x1 << (r)) | (x1 >> (32 - (r))); x1 ^= x0; }
  TF_R(13) TF_R(15) TF_R(26) TF_R(6)
  x0 += ks1; x1 += ks2 + 1u;
  TF_R(17) TF_R(29) TF_R(16) TF_R(24)
  x0 += ks2; x1 += ks0 + 2u;
  TF_R(13) TF_R(15) TF_R(26) TF_R(6)
  x0 += ks0; x1 += ks1 + 3u;
  TF_R(17) TF_R(29) TF_R(16) TF_R(24)
  x0 += ks1; x1 += ks2 + 4u;
  TF_R(13) TF_R(15) TF_R(26) TF_R(6)
  x0 += ks2; x1 += ks0 + 5u;
#undef TF_R
  return make_uint2(x0, x1);
}

// u in [0,1) exactly as jax: (bits>>9 | 0x3f800000) bitcast - 1.0f
__device__ __forceinline__ float u_from_bits(uint32_t bits) {
  return __uint_as_float((bits >> 9) | 0x3f800000u) - 1.0f;
}

// gumbel = -log(-log(u+1e-8) + 1e-8), ops ordered as the reference.
// fp-monotone nondecreasing in bits (every step is monotone).
__device__ __forceinline__ float gumbel_from_bits(uint32_t bits) {
  float u = u_from_bits(bits);
  float w = (-logf(u + 1e-8f)) + 1e-8f;
  return -logf(w);
}

// monotone float->uint map: preserves total order for non-NaN; equal iff bit-identical
__device__ __forceinline__ uint32_t mono_u32(float z) {
  uint32_t b = __float_as_uint(z);
  return b ^ ((uint32_t)(((int32_t)b) >> 31) | 0x80000000u);
}

// ---------------- zero helper ----------------
__global__ __launch_bounds__(256) void k_zero(float* __restrict__ p, int n) {
  int i = blockIdx.x * 256 + threadIdx.x;
  if (i < n) p[i] = 0.f;
}

// ---------------- c2 table + per-group threshold ----------------
// c2tab[v][k] = |c_vk|^2 (same d4-ascending tree as the old in-kernel c2a).
// thrv[v] = 2*max_k|c_vk| + 0.01  (g-space exclusion threshold; the 0.01 slack
// dominates every fp rounding in the bound chain).
__global__ __launch_bounds__(512) void k_c2(const float* __restrict__ cb,
                                            float* __restrict__ c2tab,
                                            float* __restrict__ thrv) {
  const int v = blockIdx.x, k = threadIdx.x;  // 16 x 512
  const float* cp = cb + (size_t)(v * NCODE + k) * GDIM;
  float s = 0.f;
#pragma unroll 4
  for (int d4 = 0; d4 < 16; ++d4) {
    float4 c = *(const float4*)(cp + d4 * 4);
    s += c.x * c.x + c.y * c.y + c.z * c.z + c.w * c.w;
  }
  c2tab[v * NCODE + k] = s;
  float m = s;
#pragma unroll
  for (int off = 1; off < 64; off <<= 1) m = fmaxf(m, __shfl_xor(m, off, 64));
  __shared__ float pm[8];
  if ((k & 63) == 0) pm[k >> 6] = m;
  __syncthreads();
  if (k == 0) {
    float mm = pm[0];
#pragma unroll
    for (int w = 1; w < 8; ++w) mm = fmaxf(mm, pm[w]);
    thrv[v] = 2.0f * sqrtf(mm) + 0.01f;
  }
}

// ---------------- fp32 NT GEMM, 256x64 tile, 512 thr, BK=16 ----------------
// C[M,N] = A[M,K] * B[N,K]^T + bias[N];  M=16384, N=K=1024. 8x4/thr.
// Per-WAVE inner loop identical to the measured-good round-7 kernel (4 ty
// values x 16-lane broadcast A-reads; 16-addr 2-way-free B-reads; same
// ds_write bank pattern). Block scaled to 512 thr / 256 rows: B-staging and
// B-L2-traffic halve per output element; grid 1024 = exactly 4 blocks/CU.
// BK stays 16 (BK=32 tripled bank conflicts, round-8 failure). No register
// prefetch across the compute loop (round-6 failure). Values and per-output
// k-ascending accumulation order bit-identical -> identical q bits.
// red (q2 scratch, [256][16]) overlays as[] (4096 <= 4160 floats), guarded
// by a barrier after the last as-read (round-8-verified pattern).
__global__ __launch_bounds__(512) void gemm_nt(
    const float* __restrict__ A, const float* __restrict__ B,
    const float* __restrict__ bias, float* __restrict__ C,
    const float* __restrict__ cbk, const int* __restrict__ gidx,
    float* __restrict__ q2w)
{
  __shared__ float as[16 * 260];   // [k][m], stride 260 (16640 B)
  __shared__ float bs[16 * 68];    // [k][n], stride 68  (4352 B)
  float* red = as;                 // [256][16] q2 overlay (4096 <= 4160 floats)

  const int tid = threadIdx.x;
  const int tx = tid & 15;         // n: cols tx*4..+3
  const int ty = tid >> 4;         // m: rows ty*8..+7 (0..31)
  const int m0 = blockIdx.x * 256;
  const int n0 = blockIdx.y * 64;

  float acc[8][4] = {};

  for (int kt = 0; kt < 64; ++kt) {  // 64 K-steps
    __syncthreads();
    // stage A: 2 float4 / thread (256 rows x 16 k); f -> m_l = f>>2, k4 = f&3
#pragma unroll
    for (int i = 0; i < 2; ++i) {
      int f = tid + 512 * i;
      int m_l = f >> 2, k4 = f & 3;
      const float* src;
      if (gidx) {
        int vp = kt >> 2;
        int row = gidx[(m0 + m_l) * NGRP + vp];
        src = cbk + ((size_t)(vp * NCODE + row) * GDIM + (kt & 3) * 16 + k4 * 4);
      } else {
        src = A + ((size_t)(m0 + m_l) * DIM + kt * 16 + k4 * 4);
      }
      float4 a4 = *(const float4*)src;
      as[(k4 * 4 + 0) * 260 + m_l] = a4.x;
      as[(k4 * 4 + 1) * 260 + m_l] = a4.y;
      as[(k4 * 4 + 2) * 260 + m_l] = a4.z;
      as[(k4 * 4 + 3) * 260 + m_l] = a4.w;
    }
    // stage B: 64 rows x 16 k = 256 float4, staged by tid < 256
    if (tid < 256) {
      int n_l = tid >> 2, k4 = tid & 3;
      float4 b4 = *(const float4*)(B + ((size_t)(n0 + n_l) * DIM + kt * 16 + k4 * 4));
      bs[(k4 * 4 + 0) * 68 + n_l] = b4.x;
      bs[(k4 * 4 + 1) * 68 + n_l] = b4.y;
      bs[(k4 * 4 + 2) * 68 + n_l] = b4.z;
      bs[(k4 * 4 + 3) * 68 + n_l] = b4.w;
    }
    __syncthreads();
#pragma unroll
    for (int k = 0; k < 16; ++k) {
      float4 a0 = *(const float4*)&as[k * 260 + ty * 8];
      float4 a1 = *(const float4*)&as[k * 260 + ty * 8 + 4];
      float4 b0 = *(const float4*)&bs[k * 68 + tx * 4];
      float av[8] = {a0.x, a0.y, a0.z, a0.w, a1.x, a1.y, a1.z, a1.w};
      float bv[4] = {b0.x, b0.y, b0.z, b0.w};
#pragma unroll
      for (int r = 0; r < 8; ++r)
#pragma unroll
        for (int j = 0; j < 4; ++j) acc[r][j] += av[r] * bv[j];
    }
  }

  const float4 bb = *(const float4*)(bias + n0 + tx * 4);
  if (q2w) __syncthreads();  // all as-reads done before red overlays as
#pragma unroll
  for (int r = 0; r < 8; ++r) {
    const int m = m0 + ty * 8 + r;
    float4 c;
    c.x = acc[r][0] + bb.x; c.y = acc[r][1] + bb.y;
    c.z = acc[r][2] + bb.z; c.w = acc[r][3] + bb.w;
    *(float4*)(C + (size_t)m * DIM + n0 + tx * 4) = c;
    if (q2w) red[(ty * 8 + r) * 16 + tx] = c.x * c.x + c.y * c.y + c.z * c.z + c.w * c.w;
  }
  if (q2w) {
    __syncthreads();
    if (tid < 256) {
      float s = 0.f;
#pragma unroll
      for (int x = 0; x < 16; ++x) s += red[tid * 16 + x];
      q2w[(size_t)(m0 + tid) * NGRP + blockIdx.y] = s;
    }
  }
}

// ---------------- candidate scoring helper (exact z) ----------------
__device__ __forceinline__ unsigned long long cand_key(
    const float* __restrict__ qp, const float* __restrict__ cp,
    float c2k, float q2v, uint32_t bits, int k)
{
  float acc = 0.f;
#pragma unroll 4
  for (int d4 = 0; d4 < 16; ++d4) {
    float4 qv = *(const float4*)(qp + d4 * 4);
    float4 cv = *(const float4*)(cp + d4 * 4);
    acc += qv.x * cv.x + qv.y * cv.y + qv.z * cv.z + qv.w * cv.w;
  }
  float g = gumbel_from_bits(bits);
  float z = (-sqrtf(fmaxf((q2v + c2k) - 2.0f * acc, 0.0f))) + g;
  return ((unsigned long long)mono_u32(z) << 32) | (uint32_t)(1023 - k);
}

// ---------------- K2: wave-per-token, barrier-free (round-7, verified) ----------
// grid (4096, 16), 256 thr = 4 waves. Wave wv owns token blockIdx.x*4+wv for
// group v; lane owns codes k = lane + 64*i, i=0..7. All reductions are 64-lane
// shfl butterflies: NO __syncthreads, NO LDS.
__global__ __launch_bounds__(256) void k2_select(
    const float* __restrict__ q, const float* __restrict__ q2w,
    const float* __restrict__ cb, const float* __restrict__ c2tab,
    const float* __restrict__ thrv, float* __restrict__ counts,
    int* __restrict__ idxw)
{
  const int tid = threadIdx.x;
  const int lane = tid & 63, wv = tid >> 6;
  const int v   = blockIdx.y;                  // 0..15
  const int tok = blockIdx.x * 4 + wv;         // 0..16383

  // phase A: threefry bits for my 8 codes (exact stream: ctr = base + k)
  const uint32_t base = ((uint32_t)(tok * NGRP + v)) << 9;
  uint32_t bits[8];
#pragma unroll
  for (int i = 0; i < 8; ++i) {
    uint2 r = threefry_0_42(0u, base + (uint32_t)(lane + 64 * i));
    bits[i] = r.x ^ r.y;
  }

  // phase B: wave max of bits (== max u == max g, fp-monotone)
  uint32_t m = bits[0];
#pragma unroll
  for (int i = 1; i < 8; ++i) m = bits[i] > m ? bits[i] : m;
#pragma unroll
  for (int off = 1; off < 64; off <<= 1) {
    uint32_t o = __shfl_xor(m, off, 64);
    if (o > m) m = o;
  }

  // phase C: u* threshold (wave-uniform; every lane computes it)
  const float gmax = gumbel_from_bits(m);
  const float inner = gmax - thrv[v];
  const float wstar = expf(-inner) - 1e-8f;    // > 0 since inner <= ~16
  const float ustar = expf(-wstar) - 1e-8f - 1e-6f;

  // phase D: surviving candidates evaluate exact z; packed-u64 wave argmax
  const float q2v = q2w[tok * NGRP + v];
  const float* qp = q + (size_t)tok * DIM + v * GDIM;
  unsigned long long K = 0ull;
#pragma unroll 1
  for (int i = 0; i < 8; ++i) {
    if (u_from_bits(bits[i]) >= ustar) {
      const int k = lane + 64 * i;
      unsigned long long t = cand_key(qp, cb + (size_t)(v * NCODE + k) * GDIM,
                                      c2tab[v * NCODE + k], q2v, bits[i], k);
      if (t > K) K = t;
    }
  }
#pragma unroll
  for (int off = 1; off < 64; off <<= 1) {
    unsigned long long O = __shfl_xor(K, off, 64);
    if (O > K) K = O;
  }

  if (lane == 0) {
    // fi in [0,511] always (max-bits lane passes its own filter); '&511'
    // hardens the impossible K==0 path against an OOB write.
    const int fi = (1023 - (int)(K & 0xFFFFFFFFu)) & 511;
    idxw[tok * NGRP + v] = fi;
    atomicAdd(&counts[v * NCODE + fi], 1.0f);
  }
}

// ---------------- targets ----------------
__global__ __launch_bounds__(256) void k_targets(const int* __restrict__ idxw, float* __restrict__ out) {
  int bt = blockIdx.x * 256 + threadIdx.x;  // 0..16383
  const int* p = idxw + bt * NGRP;
  int s = 0;
#pragma unroll
  for (int v = 0; v < NGRP; ++v) s += p[v] * (v * NCODE);
  out[bt] = (float)s;
}

// ---------------- diversity loss (parallel over v) ----------------
// grid (16): block v computes its entropy with the SAME per-wave butterfly and
// ascending partial sum as before (bit-identical ent_v), then atomicAdds its
// contribution 0.1*(-(ent/logK)/16). Only the final v-sum is reassociated
// (diff ~1e-9, far under tolerance). losses[0] is zeroed by k_zero first.
__global__ __launch_bounds__(512) void k_losses(const float* __restrict__ counts, float* __restrict__ out) {
  __shared__ float partial[8];
  const int k = threadIdx.x;           // 0..511
  const int v = blockIdx.x;            // 0..15
  const int lane = k & 63, wv = k >> 6;
  const float invN = 1.0f / 16384.0f;  // pow2: identical to division
  const float logK = logf(512.0f);
  float p = counts[v * NCODE + k] * invN;
  float term = p * logf(p + 1e-8f);
  float s = term;
#pragma unroll
  for (int off = 1; off < 64; off <<= 1) s += __shfl_xor(s, off, 64);
  if (lane == 0) partial[wv] = s;
  __syncthreads();
  if (k == 0) {
    float t = 0.f;
#pragma unroll
    for (int w = 0; w < 8; ++w) t += partial[w];
    float ent = -t;
    atomicAdd(out, 0.1f * (-((ent / logK) / 16.0f)));
  }
}

// ---------------- launch ----------------
extern "C" void kernel_launch(void* const* d_in, const int* in_sizes, int n_in,
                              void* d_out, int out_size, void* d_ws, size_t ws_size,
                              hipStream_t stream) {
  const float* features  = (const float*)d_in[0];  // (8,2048,1024)
  const float* codebooks = (const float*)d_in[1];  // (16,512,64)
  const float* Wq   = (const float*)d_in[2];       // (1024,1024)
  const float* bq   = (const float*)d_in[3];       // (1024)
  const float* Wout = (const float*)d_in[4];       // (1024,1024)
  const float* bout = (const float*)d_in[5];       // (1024)

  float* out = (float*)d_out;
  float* quantized = out;                 // 16,777,216
  float* targets   = out + 16777216;      // 16,384
  float* losses    = out + 16793600;      // 1

  float* ws     = (float*)d_ws;
  float* q      = ws;                     // 16,777,216 f
  float* q2w    = ws + 16777216;          // 262,144 f
  float* counts = ws + 17039360;          // 8,192 f
  int*   idxw   = (int*)(ws + 17047552);  // 262,144 i  (total 69.2 MB)

  // c2 table + thresholds live in the quantized output region as scratch;
  // k2 is the only consumer, and gemm2 (last kernel) overwrites the region.
  float* c2tab = quantized;               // 8,192 f
  float* thrv  = quantized + 8192;        // 16 f

  hipLaunchKernelGGL(k_zero, dim3(32), dim3(256), 0, stream, counts, NGRP * NCODE);
  hipLaunchKernelGGL(k_zero, dim3(1), dim3(256), 0, stream, losses, 1);
  hipLaunchKernelGGL(k_c2, dim3(16), dim3(512), 0, stream, codebooks, c2tab, thrv);
  hipLaunchKernelGGL(gemm_nt, dim3(64, 16), dim3(512), 0, stream,
                     features, Wq, bq, q, (const float*)nullptr, (const int*)nullptr, q2w);
  hipLaunchKernelGGL(k2_select, dim3(4096, 16), dim3(256), 0, stream,
                     q, q2w, codebooks, c2tab, thrv, counts, idxw);
  hipLaunchKernelGGL(k_targets, dim3(64), dim3(256), 0, stream, idxw, targets);
  hipLaunchKernelGGL(k_losses, dim3(16), dim3(512), 0, stream, counts, losses);
  hipLaunchKernelGGL(gemm_nt, dim3(64, 16), dim3(512), 0, stream,
                     (const float*)nullptr, Wout, bout, quantized, codebooks, idxw,
                     (float*)nullptr);
}

// Round 11
// 1219.423 us; speedup vs baseline: 1.1136x; 1.1121x over previous
//
#include <hip/hip_runtime.h>
#include <cstdint>
#include <cstddef>

// RNG scheme for reproducing jax.random.uniform(jax.random.key(42), (8,2048,16,512)):
//   0: threefry_partitionable (counter = (0, i)), bits = out0 ^ out1   [verified passing]
#define RNG_SCHEME 0

#define N_TOK 16384      // B*T
#define DIM   1024       // D
#define NGRP  16         // V
#define NCODE 512        // K
#define GDIM  64         // d

// ---------------- Threefry-2x32, key = (0, 42) ----------------
__device__ __forceinline__ uint2 threefry_0_42(uint32_t x0, uint32_t x1) {
  const uint32_t ks0 = 0u;
  const uint32_t ks1 = 42u;
  const uint32_t ks2 = 0x1BD11BDAu ^ 0u ^ 42u;
  x0 += ks0; x1 += ks1;
#define TF_R(r) { x0 += x1; x1 = (x1 << (r)) | (x1 >> (32 - (r))); x1 ^= x0; }
  TF_R(13) TF_R(15) TF_R(26) TF_R(6)
  x0 += ks1; x1 += ks2 + 1u;
  TF_R(17) TF_R(29) TF_R(16) TF_R(24)
  x0 += ks2; x1 += ks0 + 2u;
  TF_R(13) TF_R(15) TF_R(26) TF_R(6)
  x0 += ks0; x1 += ks1 + 3u;
  TF_R(17) TF_R(29) TF_R(16) TF_R(24)
  x0 += ks1; x1 += ks2 + 4u;
  TF_R(13) TF_R(15) TF_R(26) TF_R(6)
  x0 += ks2; x1 += ks0 + 5u;
#undef TF_R
  return make_uint2(x0, x1);
}

// u in [0,1) exactly as jax: (bits>>9 | 0x3f800000) bitcast - 1.0f
__device__ __forceinline__ float u_from_bits(uint32_t bits) {
  return __uint_as_float((bits >> 9) | 0x3f800000u) - 1.0f;
}

// gumbel = -log(-log(u+1e-8) + 1e-8), ops ordered as the reference.
// fp-monotone nondecreasing in bits (every step is monotone).
__device__ __forceinline__ float gumbel_from_bits(uint32_t bits) {
  float u = u_from_bits(bits);
  float w = (-logf(u + 1e-8f)) + 1e-8f;
  return -logf(w);
}

// monotone float->uint map: preserves total order for non-NaN; equal iff bit-identical
__device__ __forceinline__ uint32_t mono_u32(float z) {
  uint32_t b = __float_as_uint(z);
  return b ^ ((uint32_t)(((int32_t)b) >> 31) | 0x80000000u);
}

// ---------------- zero helper ----------------
__global__ __launch_bounds__(256) void k_zero(float* __restrict__ p, int n) {
  int i = blockIdx.x * 256 + threadIdx.x;
  if (i < n) p[i] = 0.f;
}

// ---------------- c2 table + per-group threshold ----------------
// c2tab[v][k] = |c_vk|^2 (same d4-ascending tree as the old in-kernel c2a).
// thrv[v] = 2*max_k|c_vk| + 0.01  (g-space exclusion threshold; the 0.01 slack
// dominates every fp rounding in the bound chain).
__global__ __launch_bounds__(512) void k_c2(const float* __restrict__ cb,
                                            float* __restrict__ c2tab,
                                            float* __restrict__ thrv) {
  const int v = blockIdx.x, k = threadIdx.x;  // 16 x 512
  const float* cp = cb + (size_t)(v * NCODE + k) * GDIM;
  float s = 0.f;
#pragma unroll 4
  for (int d4 = 0; d4 < 16; ++d4) {
    float4 c = *(const float4*)(cp + d4 * 4);
    s += c.x * c.x + c.y * c.y + c.z * c.z + c.w * c.w;
  }
  c2tab[v * NCODE + k] = s;
  float m = s;
#pragma unroll
  for (int off = 1; off < 64; off <<= 1) m = fmaxf(m, __shfl_xor(m, off, 64));
  __shared__ float pm[8];
  if ((k & 63) == 0) pm[k >> 6] = m;
  __syncthreads();
  if (k == 0) {
    float mm = pm[0];
#pragma unroll
    for (int w = 1; w < 8; ++w) mm = fmaxf(mm, pm[w]);
    thrv[v] = 2.0f * sqrtf(mm) + 0.01f;
  }
}

// ---------------- fp32 NT GEMM (round-7 verbatim: 128x64 tile, 256 thr, 8x4/thr) ----
// Single-buffer, two barriers per K-step. Measured 452 us / 44 VGPR / occ 44%.
// Four restructures failed: reg-prefetch dbuf (124 VGPR), BK=32 (3x bank
// conflicts), 128x128 (occupancy), 512-thr 256x64 (barrier width). KEEP AS IS.
__global__ __launch_bounds__(256) void gemm_nt(
    const float* __restrict__ A, const float* __restrict__ B,
    const float* __restrict__ bias, float* __restrict__ C,
    const float* __restrict__ cbk, const int* __restrict__ gidx,
    float* __restrict__ q2w)
{
  __shared__ float as[16 * 132];   // [k][m], stride 132 (pad, keeps 16B align)
  __shared__ float bs[16 * 68];    // [k][n], stride 68
  __shared__ float red[128 * 16];  // q2 reduction scratch

  const int tid = threadIdx.x;
  const int tx = tid & 15;         // n
  const int ty = tid >> 4;         // m
  const int m0 = blockIdx.x * 128;
  const int n0 = blockIdx.y * 64;

  float acc[8][4] = {};

  for (int kt = 0; kt < 64; ++kt) {
    __syncthreads();
#pragma unroll
    for (int i = 0; i < 2; ++i) {
      int f = tid + 256 * i;
      int m_l = f >> 2, k4 = f & 3;
      const float* src;
      if (gidx) {
        int vp = kt >> 2;
        int row = gidx[(m0 + m_l) * NGRP + vp];
        src = cbk + ((size_t)(vp * NCODE + row) * GDIM + (kt & 3) * 16 + k4 * 4);
      } else {
        src = A + ((size_t)(m0 + m_l) * DIM + kt * 16 + k4 * 4);
      }
      float4 a4 = *(const float4*)src;
      as[(k4 * 4 + 0) * 132 + m_l] = a4.x;
      as[(k4 * 4 + 1) * 132 + m_l] = a4.y;
      as[(k4 * 4 + 2) * 132 + m_l] = a4.z;
      as[(k4 * 4 + 3) * 132 + m_l] = a4.w;
    }
    {
      int n_l = tid >> 2, k4 = tid & 3;
      float4 b4 = *(const float4*)(B + ((size_t)(n0 + n_l) * DIM + kt * 16 + k4 * 4));
      bs[(k4 * 4 + 0) * 68 + n_l] = b4.x;
      bs[(k4 * 4 + 1) * 68 + n_l] = b4.y;
      bs[(k4 * 4 + 2) * 68 + n_l] = b4.z;
      bs[(k4 * 4 + 3) * 68 + n_l] = b4.w;
    }
    __syncthreads();
#pragma unroll
    for (int k = 0; k < 16; ++k) {
      float4 a0 = *(const float4*)&as[k * 132 + ty * 8];
      float4 a1 = *(const float4*)&as[k * 132 + ty * 8 + 4];
      float4 b0 = *(const float4*)&bs[k * 68 + tx * 4];
      float av[8] = {a0.x, a0.y, a0.z, a0.w, a1.x, a1.y, a1.z, a1.w};
      float bv[4] = {b0.x, b0.y, b0.z, b0.w};
#pragma unroll
      for (int r = 0; r < 8; ++r)
#pragma unroll
        for (int j = 0; j < 4; ++j) acc[r][j] += av[r] * bv[j];
    }
  }

  const float4 bb = *(const float4*)(bias + n0 + tx * 4);
#pragma unroll
  for (int r = 0; r < 8; ++r) {
    const int m = m0 + ty * 8 + r;
    float4 c;
    c.x = acc[r][0] + bb.x; c.y = acc[r][1] + bb.y;
    c.z = acc[r][2] + bb.z; c.w = acc[r][3] + bb.w;
    *(float4*)(C + (size_t)m * DIM + n0 + tx * 4) = c;
    if (q2w) red[(ty * 8 + r) * 16 + tx] = c.x * c.x + c.y * c.y + c.z * c.z + c.w * c.w;
  }
  if (q2w) {
    __syncthreads();
    if (tid < 128) {
      float s = 0.f;
#pragma unroll
      for (int x = 0; x < 16; ++x) s += red[tid * 16 + x];
      q2w[(size_t)(m0 + tid) * NGRP + blockIdx.y] = s;
    }
  }
}

// ---------------- candidate scoring helper (exact z) ----------------
__device__ __forceinline__ unsigned long long cand_key(
    const float* __restrict__ qp, const float* __restrict__ cp,
    float c2k, float q2v, uint32_t bits, int k)
{
  float acc = 0.f;
#pragma unroll 4
  for (int d4 = 0; d4 < 16; ++d4) {
    float4 qv = *(const float4*)(qp + d4 * 4);
    float4 cv = *(const float4*)(cp + d4 * 4);
    acc += qv.x * cv.x + qv.y * cv.y + qv.z * cv.z + qv.w * cv.w;
  }
  float g = gumbel_from_bits(bits);
  float z = (-sqrtf(fmaxf((q2v + c2k) - 2.0f * acc, 0.0f))) + g;
  return ((unsigned long long)mono_u32(z) << 32) | (uint32_t)(1023 - k);
}

// ---------------- K2: wave-per-token + single-candidate fast path ----------------
// grid (4096, 16), 256 thr = 4 waves. Wave wv owns token blockIdx.x*4+wv for
// group v; lane owns codes k = lane + 64*i, i=0..7. Reductions are 64-lane
// shfl butterflies: NO __syncthreads, NO LDS.
//
// Soundness (r5/r7-verified): any k with g_k < gmax - (2*Cmax_v + 0.01) cannot
// win argmax(-d_k + g_k). NEW: if EXACTLY ONE candidate survives the filter it
// is provably the argmax -- skip q2w/q/cb loads, the dot, sqrt/log, and the
// u64 butterfly entirely (ballot + popcount only; ~96% of waves). Ties on raw
// bits give >=2 candidates -> exact path -> first-index semantics preserved.
// The >=2-candidate path is byte-identical to the verified r7 code.
__global__ __launch_bounds__(256) void k2_select(
    const float* __restrict__ q, const float* __restrict__ q2w,
    const float* __restrict__ cb, const float* __restrict__ c2tab,
    const float* __restrict__ thrv, float* __restrict__ counts,
    int* __restrict__ idxw)
{
  const int tid = threadIdx.x;
  const int lane = tid & 63, wv = tid >> 6;
  const int v   = blockIdx.y;                  // 0..15
  const int tok = blockIdx.x * 4 + wv;         // 0..16383

  // phase A: threefry bits for my 8 codes (exact stream: ctr = base + k)
  const uint32_t base = ((uint32_t)(tok * NGRP + v)) << 9;
  uint32_t bits[8];
#pragma unroll
  for (int i = 0; i < 8; ++i) {
    uint2 r = threefry_0_42(0u, base + (uint32_t)(lane + 64 * i));
    bits[i] = r.x ^ r.y;
  }

  // phase B: wave max of bits (== max u == max g, fp-monotone)
  uint32_t m = bits[0];
#pragma unroll
  for (int i = 1; i < 8; ++i) m = bits[i] > m ? bits[i] : m;
#pragma unroll
  for (int off = 1; off < 64; off <<= 1) {
    uint32_t o = __shfl_xor(m, off, 64);
    if (o > m) m = o;
  }

  // phase C: u* threshold (wave-uniform; every lane computes it)
  const float gmax = gumbel_from_bits(m);
  const float inner = gmax - thrv[v];
  const float wstar = expf(-inner) - 1e-8f;    // > 0 since inner <= ~16
  const float ustar = expf(-wstar) - 1e-8f - 1e-6f;

  // phase D0: candidate census via ballots (wave-uniform results)
  int total = 0, win = 0;
#pragma unroll
  for (int i = 0; i < 8; ++i) {
    unsigned long long mk = __ballot(u_from_bits(bits[i]) >= ustar);
    total += __popcll(mk);
    if (mk) win = __builtin_ctzll(mk) + 64 * i;
  }

  int fi;
  if (total == 1) {
    // sole candidate == provable winner: no memory, no dot, no butterfly
    fi = win;
  } else {
    // phase D1: exact evaluation (byte-identical to the verified r7 path)
    const float q2v = q2w[tok * NGRP + v];
    const float* qp = q + (size_t)tok * DIM + v * GDIM;
    unsigned long long K = 0ull;
#pragma unroll 1
    for (int i = 0; i < 8; ++i) {
      if (u_from_bits(bits[i]) >= ustar) {
        const int k = lane + 64 * i;
        unsigned long long t = cand_key(qp, cb + (size_t)(v * NCODE + k) * GDIM,
                                        c2tab[v * NCODE + k], q2v, bits[i], k);
        if (t > K) K = t;
      }
    }
#pragma unroll
    for (int off = 1; off < 64; off <<= 1) {
      unsigned long long O = __shfl_xor(K, off, 64);
      if (O > K) K = O;
    }
    // fi in [0,511] always; '&511' hardens the impossible K==0 path.
    fi = (1023 - (int)(K & 0xFFFFFFFFu)) & 511;
  }

  if (lane == 0) {
    idxw[tok * NGRP + v] = fi;
    atomicAdd(&counts[v * NCODE + fi], 1.0f);
  }
}

// ---------------- targets ----------------
__global__ __launch_bounds__(256) void k_targets(const int* __restrict__ idxw, float* __restrict__ out) {
  int bt = blockIdx.x * 256 + threadIdx.x;  // 0..16383
  const int* p = idxw + bt * NGRP;
  int s = 0;
#pragma unroll
  for (int v = 0; v < NGRP; ++v) s += p[v] * (v * NCODE);
  out[bt] = (float)s;
}

// ---------------- diversity loss (parallel over v; r10-verified) ----------------
// grid (16): block v computes its entropy with the SAME per-wave butterfly and
// ascending partial sum as before (bit-identical ent_v), then atomicAdds its
// contribution. Only the final v-sum is reassociated (~1e-9, under tolerance).
// losses[0] is zeroed by k_zero first (replay-safe under graph capture).
__global__ __launch_bounds__(512) void k_losses(const float* __restrict__ counts, float* __restrict__ out) {
  __shared__ float partial[8];
  const int k = threadIdx.x;           // 0..511
  const int v = blockIdx.x;            // 0..15
  const int lane = k & 63, wv = k >> 6;
  const float invN = 1.0f / 16384.0f;  // pow2: identical to division
  const float logK = logf(512.0f);
  float p = counts[v * NCODE + k] * invN;
  float term = p * logf(p + 1e-8f);
  float s = term;
#pragma unroll
  for (int off = 1; off < 64; off <<= 1) s += __shfl_xor(s, off, 64);
  if (lane == 0) partial[wv] = s;
  __syncthreads();
  if (k == 0) {
    float t = 0.f;
#pragma unroll
    for (int w = 0; w < 8; ++w) t += partial[w];
    float ent = -t;
    atomicAdd(out, 0.1f * (-((ent / logK) / 16.0f)));
  }
}

// ---------------- launch ----------------
extern "C" void kernel_launch(void* const* d_in, const int* in_sizes, int n_in,
                              void* d_out, int out_size, void* d_ws, size_t ws_size,
                              hipStream_t stream) {
  const float* features  = (const float*)d_in[0];  // (8,2048,1024)
  const float* codebooks = (const float*)d_in[1];  // (16,512,64)
  const float* Wq   = (const float*)d_in[2];       // (1024,1024)
  const float* bq   = (const float*)d_in[3];       // (1024)
  const float* Wout = (const float*)d_in[4];       // (1024,1024)
  const float* bout = (const float*)d_in[5];       // (1024)

  float* out = (float*)d_out;
  float* quantized = out;                 // 16,777,216
  float* targets   = out + 16777216;      // 16,384
  float* losses    = out + 16793600;      // 1

  float* ws     = (float*)d_ws;
  float* q      = ws;                     // 16,777,216 f
  float* q2w    = ws + 16777216;          // 262,144 f
  float* counts = ws + 17039360;          // 8,192 f
  int*   idxw   = (int*)(ws + 17047552);  // 262,144 i  (total 69.2 MB)

  // c2 table + thresholds live in the quantized output region as scratch;
  // k2 is the only consumer, and gemm2 (last kernel) overwrites the region.
  float* c2tab = quantized;               // 8,192 f
  float* thrv  = quantized + 8192;        // 16 f

  hipLaunchKernelGGL(k_zero, dim3(32), dim3(256), 0, stream, counts, NGRP * NCODE);
  hipLaunchKernelGGL(k_zero, dim3(1), dim3(256), 0, stream, losses, 1);
  hipLaunchKernelGGL(k_c2, dim3(16), dim3(512), 0, stream, codebooks, c2tab, thrv);
  hipLaunchKernelGGL(gemm_nt, dim3(128, 16), dim3(256), 0, stream,
                     features, Wq, bq, q, (const float*)nullptr, (const int*)nullptr, q2w);
  hipLaunchKernelGGL(k2_select, dim3(4096, 16), dim3(256), 0, stream,
                     q, q2w, codebooks, c2tab, thrv, counts, idxw);
  hipLaunchKernelGGL(k_targets, dim3(64), dim3(256), 0, stream, idxw, targets);
  hipLaunchKernelGGL(k_losses, dim3(16), dim3(512), 0, stream, counts, losses);
  hipLaunchKernelGGL(gemm_nt, dim3(128, 16), dim3(256), 0, stream,
                     (const float*)nullptr, Wout, bout, quantized, codebooks, idxw,
                     (float*)nullptr);
}